// Round 2
// baseline (133.584 us; speedup 1.0000x reference)
//
#include <hip/hip_runtime.h>

// Bahdanau attention, fused. query [8][400][256], y [8][400][256],
// Wq_w [128][256], Wq_b [128], Wy_w [128][256], Wy_b [128], v_w [1][128],
// v_b (dropped: softmax shift-invariant), n_wins_y [8] i32. out [8][400][256] f32.
// score = sum_a v_a * tanh(qp+yp) = S_v - 2*sum_a v_a*sigmoid_like; S_v dropped
// (softmax shift-invariant). qp/yp prescaled by 2*log2(e) so exp2(qp+yp)=e^{2x}.

#define LOG2E 1.4426950408889634f
#define TANH_SCALE 2.8853900817779268f  // 2*log2(e)

constexpr int TQn = 400, TYn = 400, AD = 128, DD = 256;
constexpr int QT = 4;              // queries per fused block (1 wave each)
constexpr int QBLOCKS = TQn / QT;  // 100
constexpr int YT = 64;             // yp tile rows (score phase)
constexpr int AT = 32;             // y tile rows (apply phase)

// ---------------- projection: qp' = (query@WqT + bq)*S ; yp' likewise ----------
__global__ __launch_bounds__(256) void proj_kernel(
    const float* __restrict__ qin, const float* __restrict__ yin,
    const float* __restrict__ Wq, const float* __restrict__ bq,
    const float* __restrict__ Wy, const float* __restrict__ by,
    float* __restrict__ qp, float* __restrict__ yp)
{
    // 800 blocks: [0,400) -> q rows, [400,800) -> y rows. 8 rows/block.
    int blk = blockIdx.x;
    bool is_q = blk < 400;
    int row0 = (is_q ? blk : blk - 400) * 8;
    const float* in   = (is_q ? qin : yin) + (size_t)row0 * DD;
    const float* W    = is_q ? Wq : Wy;
    const float* bias = is_q ? bq : by;
    float* outp = (is_q ? qp : yp) + (size_t)row0 * AD;

    __shared__ float lin[8 * DD];
    {
        const float4* in4 = reinterpret_cast<const float4*>(in);
        float4* l4s = reinterpret_cast<float4*>(lin);
        for (int j = threadIdx.x; j < 8 * DD / 4; j += 256) l4s[j] = in4[j];
    }
    __syncthreads();

    int a = threadIdx.x & 127;   // attention dim
    int h = threadIdx.x >> 7;    // row half: rows h*4 .. h*4+3
    float acc[4][4] = {{0.f}};
    const float4* w4p = reinterpret_cast<const float4*>(W + (size_t)a * DD);
    const float4* l4 = reinterpret_cast<const float4*>(lin) + h * 4 * (DD / 4);
    for (int d4 = 0; d4 < DD / 4; ++d4) {
        float4 w4 = w4p[d4];
        #pragma unroll
        for (int r = 0; r < 4; ++r) {
            float4 v = l4[r * (DD / 4) + d4];  // 2-way broadcast
            acc[r][0] = fmaf(w4.x, v.x, acc[r][0]);
            acc[r][1] = fmaf(w4.y, v.y, acc[r][1]);
            acc[r][2] = fmaf(w4.z, v.z, acc[r][2]);
            acc[r][3] = fmaf(w4.w, v.w, acc[r][3]);
        }
    }
    float bb = bias[a];
    #pragma unroll
    for (int r = 0; r < 4; ++r) {
        float s = (acc[r][0] + acc[r][1]) + (acc[r][2] + acc[r][3]);
        outp[(size_t)(h * 4 + r) * AD + a] = (s + bb) * TANH_SCALE;
    }
}

// ---------------- fused scores -> masked softmax -> att @ y --------------------
__global__ __launch_bounds__(256) void fused_kernel(
    const float* __restrict__ y,    // [B][TY][DD]
    const float* __restrict__ qp,   // [B*TQ][AD] prescaled
    const float* __restrict__ yp,   // [B*TY][AD] prescaled
    const float* __restrict__ vw,   // [AD]
    const int*  __restrict__ nwins, // [B]
    float* __restrict__ out)        // [B][TQ][DD]
{
    __shared__ float4 s_qp4[QT * 32];   // 2 KB
    __shared__ float4 s_v4[32];         // 0.5 KB
    __shared__ float4 s_buf4[YT * 32];  // 32 KB: yp tile [64][32] f4 swizzled, reused as y tile [32][64] f4

    const int b  = blockIdx.x / QBLOCKS;
    const int q0 = (blockIdx.x % QBLOCKS) * QT;
    const int tid = threadIdx.x;
    const int wave = tid >> 6;   // local query
    const int lane = tid & 63;
    const int n = nwins[b];
    const float NEG_INF = -__builtin_inff();

    // stage qp tile + v (covered by first score-tile barrier)
    {
        const float4* qps = reinterpret_cast<const float4*>(qp + (size_t)(b * TQn + q0) * AD);
        if (tid < QT * 32) s_qp4[tid] = qps[tid];
        else if (tid < QT * 32 + 32) s_v4[tid - QT * 32] = reinterpret_cast<const float4*>(vw)[tid - QT * 32];
    }

    float sc[7];
    #pragma unroll
    for (int j = 0; j < 7; ++j) sc[j] = NEG_INF;

    const float4* ypb = reinterpret_cast<const float4*>(yp + (size_t)b * TYn * AD);

    // ---- score phase: 7 tiles of up to 64 t; lane <-> t, wave <-> q ----
    for (int i = 0; i < 7; ++i) {
        const int t0 = i * YT;
        const int tt = min(YT, TYn - t0);  // 64,...,64,16
        __syncthreads();                   // prior consumers of s_buf4 done
        for (int j = tid; j < tt * 32; j += 256) {
            int row = j >> 5, c = j & 31;
            s_buf4[row * 32 + (c ^ (row & 7))] = ypb[(size_t)(t0 + row) * 32 + c];
        }
        __syncthreads();
        float a0 = 0.f, a1 = 0.f, a2 = 0.f, a3 = 0.f;
        const float4* qrow = s_qp4 + wave * 32;
        const int swz = lane & 7;
        #pragma unroll 8
        for (int a4 = 0; a4 < 32; ++a4) {
            float4 yv = s_buf4[lane * 32 + (a4 ^ swz)];
            float4 qv = qrow[a4];   // wave-uniform broadcast
            float4 vv = s_v4[a4];   // broadcast
            float e, r;
            e = __builtin_amdgcn_exp2f(qv.x + yv.x); r = __builtin_amdgcn_rcpf(e + 1.f);
            a0 = fmaf(vv.x, r, a0);
            e = __builtin_amdgcn_exp2f(qv.y + yv.y); r = __builtin_amdgcn_rcpf(e + 1.f);
            a1 = fmaf(vv.y, r, a1);
            e = __builtin_amdgcn_exp2f(qv.z + yv.z); r = __builtin_amdgcn_rcpf(e + 1.f);
            a2 = fmaf(vv.z, r, a2);
            e = __builtin_amdgcn_exp2f(qv.w + yv.w); r = __builtin_amdgcn_rcpf(e + 1.f);
            a3 = fmaf(vv.w, r, a3);
        }
        if (t0 + lane < TYn)  // tile 6: lanes >=16 keep -inf (stale LDS rows discarded)
            sc[i] = -2.f * ((a0 + a1) + (a2 + a3));
    }

    // ---- mask + softmax over t (full 64-lane wave per q) ----
    #pragma unroll
    for (int j = 0; j < 7; ++j) {
        int t = j * YT + lane;
        if (t >= n) sc[j] = NEG_INF;
    }
    float m = sc[0];
    #pragma unroll
    for (int j = 1; j < 7; ++j) m = fmaxf(m, sc[j]);
    #pragma unroll
    for (int off = 32; off >= 1; off >>= 1) m = fmaxf(m, __shfl_xor(m, off, 64));
    float l = 0.f;
    #pragma unroll
    for (int j = 0; j < 7; ++j) {
        float pv = __builtin_amdgcn_exp2f((sc[j] - m) * LOG2E);  // exp2(-inf)=0
        sc[j] = pv;
        l += pv;
    }
    #pragma unroll
    for (int off = 32; off >= 1; off >>= 1) l += __shfl_xor(l, off, 64);
    float inv = 1.0f / l;
    #pragma unroll
    for (int j = 0; j < 7; ++j) sc[j] *= inv;

    // ---- apply phase: out[q][d] = sum_t p[t]*y[t][d]; lane <-> float4 col ----
    float4 acc = {0.f, 0.f, 0.f, 0.f};
    const float4* yb = reinterpret_cast<const float4*>(y + (size_t)b * TYn * DD);
    #pragma unroll
    for (int tile = 0; tile < 13; ++tile) {
        const int t0 = tile * AT;
        if (t0 >= n) break;                 // uniform
        const int tt = (tile == 12) ? 16 : 32;
        __syncthreads();                    // prior consumers of s_buf4 done
        for (int j = tid; j < tt * 64; j += 256) {
            int row = j >> 6, c = j & 63;
            s_buf4[row * 64 + c] = yb[(size_t)(t0 + row) * 64 + c];
        }
        __syncthreads();
        const int tmax = min(tt, n - t0);
        const float scj = sc[tile >> 1];    // compile-time index (full unroll)
        for (int ttl = 0; ttl < tmax; ++ttl) {
            int src = (tile & 1) * 32 + ttl;
            float pt = __int_as_float(__builtin_amdgcn_readlane(__float_as_int(scj), src));
            float4 yv = s_buf4[ttl * 64 + lane];
            acc.x = fmaf(pt, yv.x, acc.x);
            acc.y = fmaf(pt, yv.y, acc.y);
            acc.z = fmaf(pt, yv.z, acc.z);
            acc.w = fmaf(pt, yv.w, acc.w);
        }
    }
    float4* op = reinterpret_cast<float4*>(out + (size_t)(b * TQn + q0 + wave) * DD);
    op[lane] = acc;
}

extern "C" void kernel_launch(void* const* d_in, const int* in_sizes, int n_in,
                              void* d_out, int out_size, void* d_ws, size_t ws_size,
                              hipStream_t stream) {
    const float* query = (const float*)d_in[0];
    const float* y     = (const float*)d_in[1];
    const float* Wq_w  = (const float*)d_in[2];
    const float* Wq_b  = (const float*)d_in[3];
    const float* Wy_w  = (const float*)d_in[4];
    const float* Wy_b  = (const float*)d_in[5];
    const float* v_w   = (const float*)d_in[6];
    // d_in[7] = v_b: softmax-invariant, dropped.
    const int* nw      = (const int*)d_in[8];
    float* out = (float*)d_out;

    float* qp = (float*)d_ws;                    // [3200][128]
    float* yp = qp + (size_t)8 * 400 * 128;      // [3200][128]

    proj_kernel<<<800, 256, 0, stream>>>(query, y, Wq_w, Wq_b, Wy_w, Wy_b, qp, yp);
    fused_kernel<<<8 * QBLOCKS, 256, 0, stream>>>(y, qp, yp, v_w, nw, out);
}